// Round 3
// baseline (892.164 us; speedup 1.0000x reference)
//
#include <hip/hip_runtime.h>

// BinaryTreeLSTM — round 9: plane-split h/c layout + deeper A-ring.
//  * Round-8 post-mortem: 752us, MfmaUtil 3.7%, 1.12GB @ 1.49TB/s ->
//    latency-bound on A-loads AND 4.4x write amplification (h rows written
//    as 8x32B slices by different blocks -> partial-line writeback thrash).
//  * Fix 1: h/c stored PLANE-MAJOR per by-slice (h: 8 planes of n x 16 f16;
//    c: 8 planes of n/2 x 16 f32). Each 128B line written by ONE block,
//    contiguous full lines. Levels d<=4 keep row-major (plane chunks would
//    be sub-line and false-share across XCDs at the publish level).
//  * Fix 2: A-prefetch ring 2 -> 3 (more memory-level parallelism).
//  * Fix 3: barrier poll backoff s_sleep(8) -> s_sleep(32) (cut LLC flood).
//  * Everything else identical to round 8 (XCD-local dataflow, hierarchical
//    agent-scope barriers, L1-only inv, d=3 publish, XCD0 finals).

typedef _Float16 f16;
typedef f16 f16x8 __attribute__((ext_vector_type(8)));
typedef float f32x4 __attribute__((ext_vector_type(4)));

#define MAGIC 0xC0FFEEu
#define LOG2E 1.44269504f

// sync[] indices (unsigned units); lines 128B apart where contended
#define GCNT(x)  ((x) * 32)       // per-XCD ticket counters
#define TOTALI   256
#define MAGICI   257
#define DONEI    258
#define XARR(x)  (320 + (x) * 32) // per-XCD barrier arrival counters
#define GBARI    576              // global phase counter (8 per phase)
#define FBARI    608              // finals barrier (XCD0 only)

__device__ __forceinline__ float sigf(float x) {
    return __builtin_amdgcn_rcpf(1.f + __builtin_amdgcn_exp2f(-x * LOG2E));
}
__device__ __forceinline__ float tanh_fast(float x) {
    return 1.f - 2.f * __builtin_amdgcn_rcpf(1.f + __builtin_amdgcn_exp2f(2.f * x * LOG2E));
}

__device__ __forceinline__ void load_lds_16(const void* g, void* l) {
    __builtin_amdgcn_global_load_lds(
        (const __attribute__((address_space(1))) unsigned int*)g,
        (__attribute__((address_space(3))) unsigned int*)l, 16, 0, 0);
}

// Bp layout: [by(8)][kci(12)][kq(4)][c(64)][k8(8)] fp16, c = g*16 + jl,
// orig row = g*256 + by*16 + jl, orig k = kci*32 + kq*8 + k8.
__global__ __launch_bounds__(256) void pack_weights(
    const float* __restrict__ W_ih, const float* __restrict__ W_hh,
    const float* __restrict__ b_ih, const float* __restrict__ b_hh,
    f16* __restrict__ Bp, float* __restrict__ biasP)
{
    int idx = blockIdx.x * 256 + threadIdx.x;
    if (idx < 196608) {
        int by = idx / 24576;
        int r = idx - by * 24576;
        int kci = r / 2048;
        int r2 = r & 2047;
        int kq = r2 >> 9;
        int r3 = r2 & 511;
        int c = r3 >> 3;
        int k8 = r3 & 7;
        int g = c >> 4, jl = c & 15;
        int rOrig = g * 256 + by * 16 + jl;
        int kk = kci * 32 + kq * 8 + k8;
        float w = (kk < 128) ? W_ih[(size_t)rOrig * 128 + kk]
                             : W_hh[(size_t)rOrig * 256 + (kk - 128)];
        Bp[idx] = (f16)w;
    }
    if (idx < 512) {
        int by = idx >> 6, c = idx & 63;
        int g = c >> 4, jl = c & 15;
        int rOrig = g * 256 + by * 16 + jl;
        biasP[idx] = b_ih[rOrig] + b_hh[rOrig];
    }
}

// Per-level buffers: level d uses 2^d*256 B for h and for c (any layout).
__device__ __forceinline__ f16* hLvl(char* H, int d) {
    return (f16*)(H + (size_t)256u * ((1u << 18) - (1u << (d + 1))));
}
__device__ __forceinline__ float* cLvl(char* C, int d) {
    return (float*)(C + (size_t)256u * ((1u << 18) - (1u << (d + 1))));
}

// One A fragment: 8 fp16 of row `row`, k = kci*32 + kq*8 .. +8.
// kci < 4 -> fp32 embeddings converted in-register.
// kci >= 4 -> child h. AP=1: plane-major child layout; AP=0: row-major.
template <int AP>
__device__ __forceinline__ f16x8 loadA2(
    const float* __restrict__ emb, const f16* __restrict__ h_in,
    int n, int row, int kci, int kq)
{
    f16x8 r;
    if (kci < 4) {
        const float4* p = (const float4*)(emb + (size_t)(n - 1 + row) * 128 + kci * 32 + kq * 8);
        float4 a = p[0], b = p[1];
        r[0] = (f16)a.x; r[1] = (f16)a.y; r[2] = (f16)a.z; r[3] = (f16)a.w;
        r[4] = (f16)b.x; r[5] = (f16)b.y; r[6] = (f16)b.z; r[7] = (f16)b.w;
    } else if (AP) {
        int base = (kci - 4) * 32;          // compile-time after unroll
        int hi = base >> 7;                 // child row parity (k >= 128)
        int cb = base & 127;
        int pl = (cb >> 4) + (kq >> 1);     // plane 0..7
        int off = (kq & 1) * 8;
        r = *(const f16x8*)(h_in + ((size_t)pl * 2 * n + 2 * row + hi) * 16 + off);
    } else {
        r = *(const f16x8*)(h_in + (size_t)row * 256 + (kci - 4) * 32 + kq * 8);
    }
    return r;
}

// NCH: K-chunks (4 = emb only, 12 = full). CLAMP: row bounds. AP: child h/c
// plane-major. OP: output h/c plane-major.
template <int NCH, int CLAMP, int AP, int OP>
__device__ __forceinline__ void tile_compute(
    const float* __restrict__ emb, const f16* __restrict__ Bs,
    int n, int row0, int rlimit, int l15, int kq, int j, int by,
    float bi, float bfv, float bg, float bo,
    const f16* __restrict__ h_in, const float* __restrict__ c_in,
    f16* __restrict__ h_out, float* __restrict__ c_out,
    float* __restrict__ root_out)
{
    f32x4 acc[4][4];
    #pragma unroll
    for (int a = 0; a < 4; ++a)
        #pragma unroll
        for (int b = 0; b < 4; ++b) acc[a][b] = (f32x4)0.f;

    int rowm[4];
    #pragma unroll
    for (int mi = 0; mi < 4; ++mi) {
        int rr = row0 + mi * 16 + l15;
        rowm[mi] = CLAMP ? ((rr < rlimit) ? rr : (rlimit - 1)) : rr;
    }

    // depth-3 prefetch ring
    f16x8 af[3][4];
    #pragma unroll
    for (int pk = 0; pk < 3; ++pk) {
        if (pk < NCH) {
            #pragma unroll
            for (int mi = 0; mi < 4; ++mi)
                af[pk][mi] = loadA2<AP>(emb, h_in, n, rowm[mi], pk, kq);
        }
    }

    #pragma unroll
    for (int kci = 0; kci < NCH; ++kci) {
        const int sl = kci % 3;
        f16x8 bf[4];
        #pragma unroll
        for (int g = 0; g < 4; ++g)
            bf[g] = *(const f16x8*)&Bs[((kci * 4 + kq) * 64 + g * 16 + l15) * 8];
        f16x8 a0 = af[sl][0], a1 = af[sl][1], a2 = af[sl][2], a3 = af[sl][3];
        if (kci + 3 < NCH) {
            #pragma unroll
            for (int mi = 0; mi < 4; ++mi)
                af[sl][mi] = loadA2<AP>(emb, h_in, n, rowm[mi], kci + 3, kq);
        }
        #pragma unroll
        for (int g = 0; g < 4; ++g) {
            acc[0][g] = __builtin_amdgcn_mfma_f32_16x16x32_f16(a0, bf[g], acc[0][g], 0, 0, 0);
            acc[1][g] = __builtin_amdgcn_mfma_f32_16x16x32_f16(a1, bf[g], acc[1][g], 0, 0, 0);
            acc[2][g] = __builtin_amdgcn_mfma_f32_16x16x32_f16(a2, bf[g], acc[2][g], 0, 0, 0);
            acc[3][g] = __builtin_amdgcn_mfma_f32_16x16x32_f16(a3, bf[g], acc[3][g], 0, 0, 0);
        }
    }

    #pragma unroll
    for (int mi = 0; mi < 4; ++mi) {
        #pragma unroll
        for (int r = 0; r < 4; ++r) {
            int row = row0 + mi * 16 + kq * 4 + r;
            if (!CLAMP || row < rlimit) {
                float gi = acc[mi][0][r] + bi;
                float gf = acc[mi][1][r] + bfv;
                float gg = acc[mi][2][r] + bg;
                float go = acc[mi][3][r] + bo;
                float cl;
                if (NCH == 4) cl = 0.f;
                else if (AP)  cl = c_in[((size_t)by * n + row) * 16 + l15];
                else          cl = c_in[(size_t)row * 128 + j];
                float cn = sigf(gf) * cl + sigf(gi) * tanh_fast(gg);
                float hn = sigf(go) * tanh_fast(cn);
                if (root_out) {
                    root_out[j] = hn;
                    root_out[128 + j] = cn;
                } else if (OP) {
                    h_out[((size_t)by * n + row) * 16 + l15] = (f16)hn;
                    if (!(row & 1))
                        c_out[((size_t)by * (n >> 1) + (row >> 1)) * 16 + l15] = cn;
                } else {
                    h_out[(size_t)row * 128 + j] = (f16)hn;
                    if (!(row & 1))
                        c_out[(size_t)(row >> 1) * 128 + j] = cn;
                }
            }
        }
    }
}

// Hierarchical grid barrier, agent-scope counters (coherence point).
__device__ __forceinline__ void gbar(unsigned* sync, unsigned xcc,
                                     unsigned phase, unsigned Gx) {
    __syncthreads();   // per-wave vmcnt drain: all block stores are in L2
    if (threadIdx.x == 0) {
        unsigned old = __hip_atomic_fetch_add(&sync[XARR(xcc)], 1u,
                                              __ATOMIC_RELAXED, __HIP_MEMORY_SCOPE_AGENT);
        if (old == phase * Gx - 1u)
            __hip_atomic_fetch_add(&sync[GBARI], 1u,
                                   __ATOMIC_RELAXED, __HIP_MEMORY_SCOPE_AGENT);
        while (__hip_atomic_load(&sync[GBARI], __ATOMIC_RELAXED,
                                 __HIP_MEMORY_SCOPE_AGENT) < phase * 8u)
            __builtin_amdgcn_s_sleep(32);
        asm volatile("buffer_inv sc0" ::: "memory");   // L1-only invalidate
    }
    __syncthreads();
}

__global__ __launch_bounds__(256, 3) void mega(
    const float* __restrict__ emb,
    const f16* __restrict__ Bp, const float* __restrict__ biasP,
    char* __restrict__ H, char* __restrict__ C,
    float* __restrict__ root_out, unsigned* __restrict__ sync)
{
    __shared__ __align__(16) f16 Bs[24576];   // 48 KB -> 3 blocks/CU
    __shared__ unsigned meta[2];

    const int tid = threadIdx.x;
    const int lane = tid & 63;
    const int w = tid >> 6;
    const int l15 = lane & 15;
    const int kq = lane >> 4;

    unsigned xcc;
    asm volatile("s_getreg_b32 %0, hwreg(HW_REG_XCC_ID)" : "=s"(xcc));
    xcc &= 7u;

    // ---- init (poison-tolerant) + XCD ticket + global count ----
    if (blockIdx.x == 0 && tid == 0) {
        for (int x = 0; x < 8; ++x) {
            __hip_atomic_store(&sync[GCNT(x)], 0u, __ATOMIC_RELAXED, __HIP_MEMORY_SCOPE_AGENT);
            __hip_atomic_store(&sync[XARR(x)], 0u, __ATOMIC_RELAXED, __HIP_MEMORY_SCOPE_AGENT);
        }
        __hip_atomic_store(&sync[TOTALI], 0u, __ATOMIC_RELAXED, __HIP_MEMORY_SCOPE_AGENT);
        __hip_atomic_store(&sync[DONEI], 0u, __ATOMIC_RELAXED, __HIP_MEMORY_SCOPE_AGENT);
        __hip_atomic_store(&sync[GBARI], 0u, __ATOMIC_RELAXED, __HIP_MEMORY_SCOPE_AGENT);
        __hip_atomic_store(&sync[FBARI], 0u, __ATOMIC_RELAXED, __HIP_MEMORY_SCOPE_AGENT);
        __hip_atomic_store(&sync[MAGICI], MAGIC, __ATOMIC_RELEASE, __HIP_MEMORY_SCOPE_AGENT);
    }
    if (tid == 0) {
        while (__hip_atomic_load(&sync[MAGICI], __ATOMIC_RELAXED,
                                 __HIP_MEMORY_SCOPE_AGENT) != MAGIC)
            __builtin_amdgcn_s_sleep(32);
        unsigned r = __hip_atomic_fetch_add(&sync[GCNT(xcc)], 1u,
                                            __ATOMIC_RELAXED, __HIP_MEMORY_SCOPE_AGENT);
        asm volatile("s_waitcnt vmcnt(0)" ::: "memory");  // ticket visible before count
        __hip_atomic_fetch_add(&sync[TOTALI], 1u,
                               __ATOMIC_RELAXED, __HIP_MEMORY_SCOPE_AGENT);
        while (__hip_atomic_load(&sync[TOTALI], __ATOMIC_RELAXED,
                                 __HIP_MEMORY_SCOPE_AGENT) < 768u)
            __builtin_amdgcn_s_sleep(32);
        meta[0] = r;
        meta[1] = __hip_atomic_load(&sync[GCNT(xcc)], __ATOMIC_RELAXED,
                                    __HIP_MEMORY_SCOPE_AGENT);
    }
    __syncthreads();
    const unsigned rank = meta[0];
    const unsigned Gx = meta[1];             // exact blocks on this XCD
    const int by = (int)(rank & 7u);         // weight slice for whole kernel
    const int strm = (int)(rank >> 3);       // stream within (xcd, by)
    const int nstr = (int)((Gx - (unsigned)by + 7u) >> 3);

    {   // B slice -> LDS exactly once for all levels
        const char* gB = (const char*)(Bp + (size_t)by * 24576);
        char* lB = (char*)Bs;
        #pragma unroll
        for (int i = 0; i < 12; ++i)
            load_lds_16(gB + ((size_t)(i * 256 + tid)) * 16,
                        lB + ((size_t)(i * 256 + w * 64)) * 16);
    }
    __syncthreads();   // drain DMA

    const int j = by * 16 + l15;
    const float bi = biasP[by * 64 + 0 + l15];
    const float bfv = biasP[by * 64 + 16 + l15];
    const float bg = biasP[by * 64 + 32 + l15];
    const float bo = biasP[by * 64 + 48 + l15];

    // ---- XCD-local levels d=17..3 ----
    unsigned phase = 0;
    for (int d = 17; d >= 3; --d) {
        const int n = 1 << d;
        const int chunk = n >> 3;            // rows owned by this XCD
        const int base = (int)xcc * chunk;
        const f16* h_in = hLvl(H, d + 1 < 18 ? d + 1 : 17);  // d=17: unused
        const float* c_in = cLvl(C, d + 1 < 18 ? d + 1 : 17);
        f16* h_out = hLvl(H, d);
        float* c_out = cLvl(C, d);

        if (d == 17) {
            for (int t = strm; t < 64; t += nstr) {
                int row0 = base + t * 256 + w * 64;
                tile_compute<4, 0, 0, 1>(emb, Bs, n, row0, 0, l15, kq, j, by,
                                         bi, bfv, bg, bo, h_in, c_in, h_out, c_out, nullptr);
            }
        } else if (d >= 11) {
            const int T = 1 << (d - 11);     // full 256-row tiles in chunk
            for (int t = strm; t < T; t += nstr) {
                int row0 = base + t * 256 + w * 64;
                tile_compute<12, 0, 1, 1>(emb, Bs, n, row0, 0, l15, kq, j, by,
                                          bi, bfv, bg, bo, h_in, c_in, h_out, c_out, nullptr);
            }
        } else if (d >= 5) {
            if (strm == 0 && w * 64 < chunk) {
                int row0 = base + w * 64;
                tile_compute<12, 1, 1, 1>(emb, Bs, n, row0, base + chunk, l15, kq, j, by,
                                          bi, bfv, bg, bo, h_in, c_in, h_out, c_out, nullptr);
            }
        } else if (d == 4) {
            if (strm == 0 && w * 64 < chunk) {
                int row0 = base + w * 64;
                tile_compute<12, 1, 1, 0>(emb, Bs, n, row0, base + chunk, l15, kq, j, by,
                                          bi, bfv, bg, bo, h_in, c_in, h_out, c_out, nullptr);
            }
        } else {   // d == 3: child level 4 is row-major
            if (strm == 0 && w * 64 < chunk) {
                int row0 = base + w * 64;
                tile_compute<12, 1, 0, 0>(emb, Bs, n, row0, base + chunk, l15, kq, j, by,
                                          bi, bfv, bg, bo, h_in, c_in, h_out, c_out, nullptr);
            }
        }

        ++phase;
        gbar(sync, xcc, phase, Gx);
    }

    // ---- publish d=3 results cross-XCD (8 threadfences total) ----
    if (rank == 0 && tid == 0) {
        __threadfence();   // wb local L2 (holds this XCD's d=3 rows) + inv
        __hip_atomic_fetch_add(&sync[DONEI], 1u,
                               __ATOMIC_RELAXED, __HIP_MEMORY_SCOPE_AGENT);
    }

    const bool fin = (xcc == 0u) && (rank < 8u);   // by = rank, distinct
    if (!fin) return;

    if (tid == 0) {
        while (__hip_atomic_load(&sync[DONEI], __ATOMIC_RELAXED,
                                 __HIP_MEMORY_SCOPE_AGENT) < 8u)
            __builtin_amdgcn_s_sleep(32);
        __threadfence();   // acquire: invalidate local L1+L2
    }
    __syncthreads();

    // ---- finals: d=2,1,0 on 8 XCD0 blocks (levels 3,2,1 are row-major) ----
    unsigned fphase = 0;
    for (int d = 2; d >= 0; --d) {
        const int n = 1 << d;
        const f16* h_in = hLvl(H, d + 1);
        const float* c_in = cLvl(C, d + 1);
        f16* h_out = hLvl(H, d);
        float* c_out = cLvl(C, d);
        if (w == 0)
            tile_compute<12, 1, 0, 0>(emb, Bs, n, 0, n, l15, kq, j, by,
                                      bi, bfv, bg, bo, h_in, c_in, h_out, c_out,
                                      (d == 0) ? root_out : nullptr);
        if (d > 0) {
            ++fphase;
            __syncthreads();
            if (tid == 0) {
                __hip_atomic_fetch_add(&sync[FBARI], 1u,
                                       __ATOMIC_RELAXED, __HIP_MEMORY_SCOPE_AGENT);
                while (__hip_atomic_load(&sync[FBARI], __ATOMIC_RELAXED,
                                         __HIP_MEMORY_SCOPE_AGENT) < fphase * 8u)
                    __builtin_amdgcn_s_sleep(4);
                asm volatile("buffer_inv sc0" ::: "memory");
            }
            __syncthreads();
        }
    }
}

extern "C" void kernel_launch(void* const* d_in, const int* in_sizes, int n_in,
                              void* d_out, int out_size, void* d_ws, size_t ws_size,
                              hipStream_t stream) {
    const float* emb  = (const float*)d_in[0];
    const float* W_ih = (const float*)d_in[1];
    const float* W_hh = (const float*)d_in[2];
    const float* b_ih = (const float*)d_in[3];
    const float* b_hh = (const float*)d_in[4];

    char* wsb = (char*)d_ws;
    f16*   Bp    = (f16*)wsb;                      // 393216 B
    float* biasP = (float*)(wsb + 393216);         // 2048 B
    unsigned* syncp = (unsigned*)(wsb + 397312);   // 4096 B reserved
    char* H = wsb + 1048576;                       // 64 MiB per-level h
    char* C = wsb + 1048576 + 67108864;            // 64 MiB per-level c
    if (ws_size < 1048576 + 2 * 67108864) return;

    pack_weights<<<768, 256, 0, stream>>>(W_ih, W_hh, b_ih, b_hh, Bp, biasP);
    mega<<<768, 256, 0, stream>>>(emb, Bp, biasP, H, C, (float*)d_out, syncp);
}

// Round 5
// 695.267 us; speedup vs baseline: 1.2832x; 1.2832x over previous
//
#include <hip/hip_runtime.h>

// BinaryTreeLSTM — round 11: round-9 skeleton + live prefetch ring.
//  * Round-10 post-mortem: hang. The only structural novelty was workgroup-
//    scope atomics on global memory for inter-workgroup sync — outside the
//    memory model (stale XCD-L2 lines never observe agent-scope init).
//    Reverted: ALL sync is round-9's proven agent-scope machinery.
//  * Ring theory (untested by round 10) retried with minimal delta:
//    - RING 3 -> 6, __launch_bounds__(256,2) (VGPR cap 256 so the ring is
//      not latency-sunk; round 9's VGPR_Count=84 proved the sink), grid 512
//      (2 blocks/CU, co-residency capacity-guaranteed: 96KB LDS, <=256 VGPR).
//    - c_in prefetched at tile start (epilogue load chain hidden).
//  * Verification signal: VGPR_Count must jump to ~200+. If still ~84, the
//    sink theory is wrong -> next lever is LDS-staged A via global_load_lds.

typedef _Float16 f16;
typedef f16 f16x8 __attribute__((ext_vector_type(8)));
typedef float f32x4 __attribute__((ext_vector_type(4)));

#define MAGIC 0xC0FFEEu
#define LOG2E 1.44269504f
#define RING 6

// sync[] indices (unsigned units); lines 128B apart where contended
#define GCNT(x)  ((x) * 32)       // per-XCD ticket counters
#define TOTALI   256
#define MAGICI   257
#define DONEI    258
#define XARR(x)  (320 + (x) * 32) // per-XCD barrier arrival counters
#define GBARI    576              // global phase counter (8 per phase)
#define FBARI    608              // finals barrier (XCD0 only)

__device__ __forceinline__ float sigf(float x) {
    return __builtin_amdgcn_rcpf(1.f + __builtin_amdgcn_exp2f(-x * LOG2E));
}
__device__ __forceinline__ float tanh_fast(float x) {
    return 1.f - 2.f * __builtin_amdgcn_rcpf(1.f + __builtin_amdgcn_exp2f(2.f * x * LOG2E));
}

__device__ __forceinline__ void load_lds_16(const void* g, void* l) {
    __builtin_amdgcn_global_load_lds(
        (const __attribute__((address_space(1))) unsigned int*)g,
        (__attribute__((address_space(3))) unsigned int*)l, 16, 0, 0);
}

// Bp layout: [by(8)][kci(12)][kq(4)][c(64)][k8(8)] fp16, c = g*16 + jl,
// orig row = g*256 + by*16 + jl, orig k = kci*32 + kq*8 + k8.
__global__ __launch_bounds__(256) void pack_weights(
    const float* __restrict__ W_ih, const float* __restrict__ W_hh,
    const float* __restrict__ b_ih, const float* __restrict__ b_hh,
    f16* __restrict__ Bp, float* __restrict__ biasP)
{
    int idx = blockIdx.x * 256 + threadIdx.x;
    if (idx < 196608) {
        int by = idx / 24576;
        int r = idx - by * 24576;
        int kci = r / 2048;
        int r2 = r & 2047;
        int kq = r2 >> 9;
        int r3 = r2 & 511;
        int c = r3 >> 3;
        int k8 = r3 & 7;
        int g = c >> 4, jl = c & 15;
        int rOrig = g * 256 + by * 16 + jl;
        int kk = kci * 32 + kq * 8 + k8;
        float w = (kk < 128) ? W_ih[(size_t)rOrig * 128 + kk]
                             : W_hh[(size_t)rOrig * 256 + (kk - 128)];
        Bp[idx] = (f16)w;
    }
    if (idx < 512) {
        int by = idx >> 6, c = idx & 63;
        int g = c >> 4, jl = c & 15;
        int rOrig = g * 256 + by * 16 + jl;
        biasP[idx] = b_ih[rOrig] + b_hh[rOrig];
    }
}

// Per-level buffers: level d uses 2^d*256 B for h and for c (any layout).
__device__ __forceinline__ f16* hLvl(char* H, int d) {
    return (f16*)(H + (size_t)256u * ((1u << 18) - (1u << (d + 1))));
}
__device__ __forceinline__ float* cLvl(char* C, int d) {
    return (float*)(C + (size_t)256u * ((1u << 18) - (1u << (d + 1))));
}

// One A fragment: 8 fp16 of row `row`, k = kci*32 + kq*8 .. +8.
// kci < 4 -> fp32 embeddings converted in-register.
// kci >= 4 -> child h. AP=1: plane-major child layout; AP=0: row-major.
template <int AP>
__device__ __forceinline__ f16x8 loadA2(
    const float* __restrict__ emb, const f16* __restrict__ h_in,
    int n, int row, int kci, int kq)
{
    f16x8 r;
    if (kci < 4) {
        const float4* p = (const float4*)(emb + (size_t)(n - 1 + row) * 128 + kci * 32 + kq * 8);
        float4 a = p[0], b = p[1];
        r[0] = (f16)a.x; r[1] = (f16)a.y; r[2] = (f16)a.z; r[3] = (f16)a.w;
        r[4] = (f16)b.x; r[5] = (f16)b.y; r[6] = (f16)b.z; r[7] = (f16)b.w;
    } else if (AP) {
        int base = (kci - 4) * 32;          // compile-time after unroll
        int hi = base >> 7;                 // child row parity (k >= 128)
        int cb = base & 127;
        int pl = (cb >> 4) + (kq >> 1);     // plane 0..7
        int off = (kq & 1) * 8;
        r = *(const f16x8*)(h_in + ((size_t)pl * 2 * n + 2 * row + hi) * 16 + off);
    } else {
        r = *(const f16x8*)(h_in + (size_t)row * 256 + (kci - 4) * 32 + kq * 8);
    }
    return r;
}

// NCH: K-chunks (4 = emb only, 12 = full). CLAMP: row bounds. AP: child h/c
// plane-major. OP: output h/c plane-major.
template <int NCH, int CLAMP, int AP, int OP>
__device__ __forceinline__ void tile_compute(
    const float* __restrict__ emb, const f16* __restrict__ Bs,
    int n, int row0, int rlimit, int l15, int kq, int j, int by,
    float bi, float bfv, float bg, float bo,
    const f16* __restrict__ h_in, const float* __restrict__ c_in,
    f16* __restrict__ h_out, float* __restrict__ c_out,
    float* __restrict__ root_out)
{
    f32x4 acc[4][4];
    #pragma unroll
    for (int a = 0; a < 4; ++a)
        #pragma unroll
        for (int b = 0; b < 4; ++b) acc[a][b] = (f32x4)0.f;

    int rowm[4];
    #pragma unroll
    for (int mi = 0; mi < 4; ++mi) {
        int rr = row0 + mi * 16 + l15;
        rowm[mi] = CLAMP ? ((rr < rlimit) ? rr : (rlimit - 1)) : rr;
    }

    // c_in prefetch: issued with the prologue, consumed in the epilogue.
    float cpre[4][4];
    if (NCH == 12) {
        #pragma unroll
        for (int mi = 0; mi < 4; ++mi) {
            #pragma unroll
            for (int r = 0; r < 4; ++r) {
                int row = row0 + mi * 16 + kq * 4 + r;
                int rc = CLAMP ? ((row < rlimit) ? row : (rlimit - 1)) : row;
                cpre[mi][r] = AP ? c_in[((size_t)by * n + rc) * 16 + l15]
                                 : c_in[(size_t)rc * 128 + j];
            }
        }
    }

    // depth-RING prefetch ring (VGPR cap 256 -> ring stays in registers)
    f16x8 af[RING][4];
    #pragma unroll
    for (int pk = 0; pk < RING; ++pk) {
        if (pk < NCH) {
            #pragma unroll
            for (int mi = 0; mi < 4; ++mi)
                af[pk][mi] = loadA2<AP>(emb, h_in, n, rowm[mi], pk, kq);
        }
    }

    #pragma unroll
    for (int kci = 0; kci < NCH; ++kci) {
        const int sl = kci % RING;
        f16x8 bf[4];
        #pragma unroll
        for (int g = 0; g < 4; ++g)
            bf[g] = *(const f16x8*)&Bs[((kci * 4 + kq) * 64 + g * 16 + l15) * 8];
        f16x8 a0 = af[sl][0], a1 = af[sl][1], a2 = af[sl][2], a3 = af[sl][3];
        if (kci + RING < NCH) {
            #pragma unroll
            for (int mi = 0; mi < 4; ++mi)
                af[sl][mi] = loadA2<AP>(emb, h_in, n, rowm[mi], kci + RING, kq);
        }
        #pragma unroll
        for (int g = 0; g < 4; ++g) {
            acc[0][g] = __builtin_amdgcn_mfma_f32_16x16x32_f16(a0, bf[g], acc[0][g], 0, 0, 0);
            acc[1][g] = __builtin_amdgcn_mfma_f32_16x16x32_f16(a1, bf[g], acc[1][g], 0, 0, 0);
            acc[2][g] = __builtin_amdgcn_mfma_f32_16x16x32_f16(a2, bf[g], acc[2][g], 0, 0, 0);
            acc[3][g] = __builtin_amdgcn_mfma_f32_16x16x32_f16(a3, bf[g], acc[3][g], 0, 0, 0);
        }
    }

    #pragma unroll
    for (int mi = 0; mi < 4; ++mi) {
        #pragma unroll
        for (int r = 0; r < 4; ++r) {
            int row = row0 + mi * 16 + kq * 4 + r;
            if (!CLAMP || row < rlimit) {
                float gi = acc[mi][0][r] + bi;
                float gf = acc[mi][1][r] + bfv;
                float gg = acc[mi][2][r] + bg;
                float go = acc[mi][3][r] + bo;
                float cl = (NCH == 4) ? 0.f : cpre[mi][r];
                float cn = sigf(gf) * cl + sigf(gi) * tanh_fast(gg);
                float hn = sigf(go) * tanh_fast(cn);
                if (root_out) {
                    root_out[j] = hn;
                    root_out[128 + j] = cn;
                } else if (OP) {
                    h_out[((size_t)by * n + row) * 16 + l15] = (f16)hn;
                    if (!(row & 1))
                        c_out[((size_t)by * (n >> 1) + (row >> 1)) * 16 + l15] = cn;
                } else {
                    h_out[(size_t)row * 128 + j] = (f16)hn;
                    if (!(row & 1))
                        c_out[(size_t)(row >> 1) * 128 + j] = cn;
                }
            }
        }
    }
}

// Hierarchical grid barrier, agent-scope counters (coherence point).
// Proven in rounds 8/9 — unchanged.
__device__ __forceinline__ void gbar(unsigned* sync, unsigned xcc,
                                     unsigned phase, unsigned Gx) {
    __syncthreads();   // per-wave vmcnt drain: all block stores are in L2
    if (threadIdx.x == 0) {
        unsigned old = __hip_atomic_fetch_add(&sync[XARR(xcc)], 1u,
                                              __ATOMIC_RELAXED, __HIP_MEMORY_SCOPE_AGENT);
        if (old == phase * Gx - 1u)
            __hip_atomic_fetch_add(&sync[GBARI], 1u,
                                   __ATOMIC_RELAXED, __HIP_MEMORY_SCOPE_AGENT);
        while (__hip_atomic_load(&sync[GBARI], __ATOMIC_RELAXED,
                                 __HIP_MEMORY_SCOPE_AGENT) < phase * 8u)
            __builtin_amdgcn_s_sleep(32);
        asm volatile("buffer_inv sc0" ::: "memory");   // L1-only invalidate
    }
    __syncthreads();
}

__global__ __launch_bounds__(256, 2) void mega(
    const float* __restrict__ emb,
    const f16* __restrict__ Bp, const float* __restrict__ biasP,
    char* __restrict__ H, char* __restrict__ C,
    float* __restrict__ root_out, unsigned* __restrict__ sync)
{
    __shared__ __align__(16) f16 Bs[24576];   // 48 KB -> 2 blocks/CU w/ (256,2)
    __shared__ unsigned meta[2];

    const int tid = threadIdx.x;
    const int lane = tid & 63;
    const int w = tid >> 6;
    const int l15 = lane & 15;
    const int kq = lane >> 4;

    unsigned xcc;
    asm volatile("s_getreg_b32 %0, hwreg(HW_REG_XCC_ID)" : "=s"(xcc));
    xcc &= 7u;

    // ---- init (poison-tolerant) + XCD ticket + global count ----
    if (blockIdx.x == 0 && tid == 0) {
        for (int x = 0; x < 8; ++x) {
            __hip_atomic_store(&sync[GCNT(x)], 0u, __ATOMIC_RELAXED, __HIP_MEMORY_SCOPE_AGENT);
            __hip_atomic_store(&sync[XARR(x)], 0u, __ATOMIC_RELAXED, __HIP_MEMORY_SCOPE_AGENT);
        }
        __hip_atomic_store(&sync[TOTALI], 0u, __ATOMIC_RELAXED, __HIP_MEMORY_SCOPE_AGENT);
        __hip_atomic_store(&sync[DONEI], 0u, __ATOMIC_RELAXED, __HIP_MEMORY_SCOPE_AGENT);
        __hip_atomic_store(&sync[GBARI], 0u, __ATOMIC_RELAXED, __HIP_MEMORY_SCOPE_AGENT);
        __hip_atomic_store(&sync[FBARI], 0u, __ATOMIC_RELAXED, __HIP_MEMORY_SCOPE_AGENT);
        __hip_atomic_store(&sync[MAGICI], MAGIC, __ATOMIC_RELEASE, __HIP_MEMORY_SCOPE_AGENT);
    }
    if (tid == 0) {
        while (__hip_atomic_load(&sync[MAGICI], __ATOMIC_RELAXED,
                                 __HIP_MEMORY_SCOPE_AGENT) != MAGIC)
            __builtin_amdgcn_s_sleep(32);
        unsigned r = __hip_atomic_fetch_add(&sync[GCNT(xcc)], 1u,
                                            __ATOMIC_RELAXED, __HIP_MEMORY_SCOPE_AGENT);
        asm volatile("s_waitcnt vmcnt(0)" ::: "memory");  // ticket visible before count
        __hip_atomic_fetch_add(&sync[TOTALI], 1u,
                               __ATOMIC_RELAXED, __HIP_MEMORY_SCOPE_AGENT);
        while (__hip_atomic_load(&sync[TOTALI], __ATOMIC_RELAXED,
                                 __HIP_MEMORY_SCOPE_AGENT) < 512u)
            __builtin_amdgcn_s_sleep(32);
        meta[0] = r;
        meta[1] = __hip_atomic_load(&sync[GCNT(xcc)], __ATOMIC_RELAXED,
                                    __HIP_MEMORY_SCOPE_AGENT);
    }
    __syncthreads();
    const unsigned rank = meta[0];
    const unsigned Gx = meta[1];             // exact blocks on this XCD (~64)
    const int by = (int)(rank & 7u);         // weight slice for whole kernel
    const int strm = (int)(rank >> 3);       // stream within (xcd, by)
    const int nstr = (int)((Gx - (unsigned)by + 7u) >> 3);

    {   // B slice -> LDS exactly once for all levels
        const char* gB = (const char*)(Bp + (size_t)by * 24576);
        char* lB = (char*)Bs;
        #pragma unroll
        for (int i = 0; i < 12; ++i)
            load_lds_16(gB + ((size_t)(i * 256 + tid)) * 16,
                        lB + ((size_t)(i * 256 + w * 64)) * 16);
    }
    __syncthreads();   // drain DMA

    const int j = by * 16 + l15;
    const float bi = biasP[by * 64 + 0 + l15];
    const float bfv = biasP[by * 64 + 16 + l15];
    const float bg = biasP[by * 64 + 32 + l15];
    const float bo = biasP[by * 64 + 48 + l15];

    // ---- XCD-local levels d=17..3 ----
    unsigned phase = 0;
    for (int d = 17; d >= 3; --d) {
        const int n = 1 << d;
        const int chunk = n >> 3;            // rows owned by this XCD
        const int base = (int)xcc * chunk;
        const f16* h_in = hLvl(H, d + 1 < 18 ? d + 1 : 17);  // d=17: unused
        const float* c_in = cLvl(C, d + 1 < 18 ? d + 1 : 17);
        f16* h_out = hLvl(H, d);
        float* c_out = cLvl(C, d);

        if (d == 17) {
            for (int t = strm; t < 64; t += nstr) {
                int row0 = base + t * 256 + w * 64;
                tile_compute<4, 0, 0, 1>(emb, Bs, n, row0, 0, l15, kq, j, by,
                                         bi, bfv, bg, bo, h_in, c_in, h_out, c_out, nullptr);
            }
        } else if (d >= 11) {
            const int T = 1 << (d - 11);     // full 256-row tiles in chunk
            for (int t = strm; t < T; t += nstr) {
                int row0 = base + t * 256 + w * 64;
                tile_compute<12, 0, 1, 1>(emb, Bs, n, row0, 0, l15, kq, j, by,
                                          bi, bfv, bg, bo, h_in, c_in, h_out, c_out, nullptr);
            }
        } else if (d >= 5) {
            if (strm == 0 && w * 64 < chunk) {
                int row0 = base + w * 64;
                tile_compute<12, 1, 1, 1>(emb, Bs, n, row0, base + chunk, l15, kq, j, by,
                                          bi, bfv, bg, bo, h_in, c_in, h_out, c_out, nullptr);
            }
        } else if (d == 4) {
            if (strm == 0 && w * 64 < chunk) {
                int row0 = base + w * 64;
                tile_compute<12, 1, 1, 0>(emb, Bs, n, row0, base + chunk, l15, kq, j, by,
                                          bi, bfv, bg, bo, h_in, c_in, h_out, c_out, nullptr);
            }
        } else {   // d == 3: child level 4 is row-major
            if (strm == 0 && w * 64 < chunk) {
                int row0 = base + w * 64;
                tile_compute<12, 1, 0, 0>(emb, Bs, n, row0, base + chunk, l15, kq, j, by,
                                          bi, bfv, bg, bo, h_in, c_in, h_out, c_out, nullptr);
            }
        }

        ++phase;
        gbar(sync, xcc, phase, Gx);
    }

    // ---- publish d=3 results cross-XCD (8 threadfences total) ----
    if (rank == 0 && tid == 0) {
        __threadfence();   // wb local L2 (holds this XCD's d=3 rows) + inv
        __hip_atomic_fetch_add(&sync[DONEI], 1u,
                               __ATOMIC_RELAXED, __HIP_MEMORY_SCOPE_AGENT);
    }

    const bool fin = (xcc == 0u) && (rank < 8u);   // by = rank, distinct
    if (!fin) return;

    if (tid == 0) {
        while (__hip_atomic_load(&sync[DONEI], __ATOMIC_RELAXED,
                                 __HIP_MEMORY_SCOPE_AGENT) < 8u)
            __builtin_amdgcn_s_sleep(32);
        __threadfence();   // acquire: invalidate local L1+L2
    }
    __syncthreads();

    // ---- finals: d=2,1,0 on 8 XCD0 blocks (levels 3,2,1 are row-major) ----
    unsigned fphase = 0;
    for (int d = 2; d >= 0; --d) {
        const int n = 1 << d;
        const f16* h_in = hLvl(H, d + 1);
        const float* c_in = cLvl(C, d + 1);
        f16* h_out = hLvl(H, d);
        float* c_out = cLvl(C, d);
        if (w == 0)
            tile_compute<12, 1, 0, 0>(emb, Bs, n, 0, n, l15, kq, j, by,
                                      bi, bfv, bg, bo, h_in, c_in, h_out, c_out,
                                      (d == 0) ? root_out : nullptr);
        if (d > 0) {
            ++fphase;
            __syncthreads();
            if (tid == 0) {
                __hip_atomic_fetch_add(&sync[FBARI], 1u,
                                       __ATOMIC_RELAXED, __HIP_MEMORY_SCOPE_AGENT);
                while (__hip_atomic_load(&sync[FBARI], __ATOMIC_RELAXED,
                                         __HIP_MEMORY_SCOPE_AGENT) < fphase * 8u)
                    __builtin_amdgcn_s_sleep(4);
                asm volatile("buffer_inv sc0" ::: "memory");
            }
            __syncthreads();
        }
    }
}

extern "C" void kernel_launch(void* const* d_in, const int* in_sizes, int n_in,
                              void* d_out, int out_size, void* d_ws, size_t ws_size,
                              hipStream_t stream) {
    const float* emb  = (const float*)d_in[0];
    const float* W_ih = (const float*)d_in[1];
    const float* W_hh = (const float*)d_in[2];
    const float* b_ih = (const float*)d_in[3];
    const float* b_hh = (const float*)d_in[4];

    char* wsb = (char*)d_ws;
    f16*   Bp    = (f16*)wsb;                      // 393216 B
    float* biasP = (float*)(wsb + 393216);         // 2048 B
    unsigned* syncp = (unsigned*)(wsb + 397312);   // 4096 B reserved
    char* H = wsb + 1048576;                       // 64 MiB per-level h
    char* C = wsb + 1048576 + 67108864;            // 64 MiB per-level c
    if (ws_size < 1048576 + 2 * 67108864) return;

    pack_weights<<<768, 256, 0, stream>>>(W_ih, W_hh, b_ih, b_hh, Bp, biasP);
    mega<<<512, 256, 0, stream>>>(emb, Bp, biasP, H, C, (float*)d_out, syncp);
}

// Round 6
// 461.479 us; speedup vs baseline: 1.9333x; 1.5066x over previous
//
#include <hip/hip_runtime.h>

// BinaryTreeLSTM — round 12: LDS-staged A via global_load_lds (counted vmcnt).
//  * Rounds 8-11 all plateau at 1.48 TB/s: register A-ring can't hold enough
//    bytes in flight (VGPR-bound; compiler sinks the ring). Fix: stage A
//    through per-WAVE double-buffered LDS slabs with global_load_lds DMA —
//    in-flight bytes live in the DMA queue, not VGPRs. No barriers in K-loop.
//  * vmcnt discipline: stage k+2 after lgkmcnt(0); s_waitcnt vmcnt(4) at top
//    of each chunk (never 0 mid-loop); sched_barrier(0) after each wait.
//  * emb pre-converted to f16 (emb_cvt, round-6-proven) -> uniform staging.
//  * h stored parity-split plane-major: [plane 8][parity 2][n/2 rows][32B];
//    left/right-child chunk reads are dense rows (was 50% line util).
//  * LDS = 48KB B + 4 waves x 2 x 4KB A = 81920 B exactly -> 2 blocks/CU.
//  * Sync skeleton (agent-scope hierarchical barriers, ticket, publish,
//    finals) byte-identical to round 11 (proven).

typedef _Float16 f16;
typedef f16 f16x8 __attribute__((ext_vector_type(8)));
typedef float f32x4 __attribute__((ext_vector_type(4)));

#define MAGIC 0xC0FFEEu
#define LOG2E 1.44269504f
#define RING 6

// sync[] indices (unsigned units); lines 128B apart where contended
#define GCNT(x)  ((x) * 32)
#define TOTALI   256
#define MAGICI   257
#define DONEI    258
#define XARR(x)  (320 + (x) * 32)
#define GBARI    576
#define FBARI    608

__device__ __forceinline__ float sigf(float x) {
    return __builtin_amdgcn_rcpf(1.f + __builtin_amdgcn_exp2f(-x * LOG2E));
}
__device__ __forceinline__ float tanh_fast(float x) {
    return 1.f - 2.f * __builtin_amdgcn_rcpf(1.f + __builtin_amdgcn_exp2f(2.f * x * LOG2E));
}

__device__ __forceinline__ void load_lds_16(const void* g, void* l) {
    __builtin_amdgcn_global_load_lds(
        (const __attribute__((address_space(1))) unsigned int*)g,
        (__attribute__((address_space(3))) unsigned int*)l, 16, 0, 0);
}

// Bp layout: [by(8)][kci(12)][kq(4)][c(64)][k8(8)] fp16.
__global__ __launch_bounds__(256) void pack_weights(
    const float* __restrict__ W_ih, const float* __restrict__ W_hh,
    const float* __restrict__ b_ih, const float* __restrict__ b_hh,
    f16* __restrict__ Bp, float* __restrict__ biasP)
{
    int idx = blockIdx.x * 256 + threadIdx.x;
    if (idx < 196608) {
        int by = idx / 24576;
        int r = idx - by * 24576;
        int kci = r / 2048;
        int r2 = r & 2047;
        int kq = r2 >> 9;
        int r3 = r2 & 511;
        int c = r3 >> 3;
        int k8 = r3 & 7;
        int g = c >> 4, jl = c & 15;
        int rOrig = g * 256 + by * 16 + jl;
        int kk = kci * 32 + kq * 8 + k8;
        float w = (kk < 128) ? W_ih[(size_t)rOrig * 128 + kk]
                             : W_hh[(size_t)rOrig * 256 + (kk - 128)];
        Bp[idx] = (f16)w;
    }
    if (idx < 512) {
        int by = idx >> 6, c = idx & 63;
        int g = c >> 4, jl = c & 15;
        int rOrig = g * 256 + by * 16 + jl;
        biasP[idx] = b_ih[rOrig] + b_hh[rOrig];
    }
}

// emb fp32 -> fp16, 8 elems/thread. 262143*128 = 33554304 elems.
__global__ __launch_bounds__(256) void emb_cvt(
    const float* __restrict__ emb, f16* __restrict__ embH)
{
    int i = blockIdx.x * 256 + threadIdx.x;
    if (i < 4194288) {
        const float4 a = *(const float4*)(emb + (size_t)i * 8);
        const float4 b = *(const float4*)(emb + (size_t)i * 8 + 4);
        f16x8 r;
        r[0] = (f16)a.x; r[1] = (f16)a.y; r[2] = (f16)a.z; r[3] = (f16)a.w;
        r[4] = (f16)b.x; r[5] = (f16)b.y; r[6] = (f16)b.z; r[7] = (f16)b.w;
        *(f16x8*)(embH + (size_t)i * 8) = r;
    }
}

// Per-level buffers: level d uses 2^d*256 B for h and for c.
__device__ __forceinline__ f16* hLvl(char* H, int d) {
    return (f16*)(H + (size_t)256u * ((1u << 18) - (1u << (d + 1))));
}
__device__ __forceinline__ float* cLvl(char* C, int d) {
    return (float*)(C + (size_t)256u * ((1u << 18) - (1u << (d + 1))));
}

// ---------------- register-path tile (small levels only) ----------------
// AP: 0 = row-major child h, 2 = parity-split plane-major child h.
// OP: 0 = row-major out, 1 = parity-split plane-major out.
template <int AP>
__device__ __forceinline__ f16x8 loadA2(
    const f16* __restrict__ embH, const f16* __restrict__ h_in,
    int n, int row, int kci, int kq)
{
    f16x8 r;
    if (kci < 4) {
        r = *(const f16x8*)(embH + (size_t)(n - 1 + row) * 128 + kci * 32 + kq * 8);
    } else if (AP == 2) {
        int base = (kci - 4) * 32;
        int par = base >> 7;
        int cb = base & 127;
        int pl = (cb >> 4) + (kq >> 1);
        int off = (kq & 1) * 8;
        r = *(const f16x8*)(h_in + ((size_t)pl * 2 * n + (size_t)par * n + row) * 16 + off);
    } else {
        r = *(const f16x8*)(h_in + (size_t)row * 256 + (kci - 4) * 32 + kq * 8);
    }
    return r;
}

template <int NCH, int CLAMP, int AP, int OP>
__device__ __forceinline__ void tile_compute(
    const f16* __restrict__ embH, const f16* __restrict__ Bs,
    int n, int row0, int rlimit, int l15, int kq, int j, int by,
    float bi, float bfv, float bg, float bo,
    const f16* __restrict__ h_in, const float* __restrict__ c_in,
    f16* __restrict__ h_out, float* __restrict__ c_out,
    float* __restrict__ root_out)
{
    f32x4 acc[4][4];
    #pragma unroll
    for (int a = 0; a < 4; ++a)
        #pragma unroll
        for (int b = 0; b < 4; ++b) acc[a][b] = (f32x4)0.f;

    int rowm[4];
    #pragma unroll
    for (int mi = 0; mi < 4; ++mi) {
        int rr = row0 + mi * 16 + l15;
        rowm[mi] = CLAMP ? ((rr < rlimit) ? rr : (rlimit - 1)) : rr;
    }

    float cpre[4][4];
    if (NCH == 12) {
        #pragma unroll
        for (int mi = 0; mi < 4; ++mi) {
            #pragma unroll
            for (int r = 0; r < 4; ++r) {
                int row = row0 + mi * 16 + kq * 4 + r;
                int rc = CLAMP ? ((row < rlimit) ? row : (rlimit - 1)) : row;
                cpre[mi][r] = (AP == 2) ? c_in[((size_t)by * n + rc) * 16 + l15]
                                        : c_in[(size_t)rc * 128 + j];
            }
        }
    }

    f16x8 af[RING][4];
    #pragma unroll
    for (int pk = 0; pk < RING; ++pk) {
        if (pk < NCH) {
            #pragma unroll
            for (int mi = 0; mi < 4; ++mi)
                af[pk][mi] = loadA2<AP>(embH, h_in, n, rowm[mi], pk, kq);
        }
    }

    #pragma unroll
    for (int kci = 0; kci < NCH; ++kci) {
        const int sl = kci % RING;
        f16x8 bf[4];
        #pragma unroll
        for (int g = 0; g < 4; ++g)
            bf[g] = *(const f16x8*)&Bs[((kci * 4 + kq) * 64 + g * 16 + l15) * 8];
        f16x8 a0 = af[sl][0], a1 = af[sl][1], a2 = af[sl][2], a3 = af[sl][3];
        if (kci + RING < NCH) {
            #pragma unroll
            for (int mi = 0; mi < 4; ++mi)
                af[sl][mi] = loadA2<AP>(embH, h_in, n, rowm[mi], kci + RING, kq);
        }
        #pragma unroll
        for (int g = 0; g < 4; ++g) {
            acc[0][g] = __builtin_amdgcn_mfma_f32_16x16x32_f16(a0, bf[g], acc[0][g], 0, 0, 0);
            acc[1][g] = __builtin_amdgcn_mfma_f32_16x16x32_f16(a1, bf[g], acc[1][g], 0, 0, 0);
            acc[2][g] = __builtin_amdgcn_mfma_f32_16x16x32_f16(a2, bf[g], acc[2][g], 0, 0, 0);
            acc[3][g] = __builtin_amdgcn_mfma_f32_16x16x32_f16(a3, bf[g], acc[3][g], 0, 0, 0);
        }
    }

    #pragma unroll
    for (int mi = 0; mi < 4; ++mi) {
        #pragma unroll
        for (int r = 0; r < 4; ++r) {
            int row = row0 + mi * 16 + kq * 4 + r;
            if (!CLAMP || row < rlimit) {
                float gi = acc[mi][0][r] + bi;
                float gf = acc[mi][1][r] + bfv;
                float gg = acc[mi][2][r] + bg;
                float go = acc[mi][3][r] + bo;
                float cl = (NCH == 4) ? 0.f : cpre[mi][r];
                float cn = sigf(gf) * cl + sigf(gi) * tanh_fast(gg);
                float hn = sigf(go) * tanh_fast(cn);
                if (root_out) {
                    root_out[j] = hn;
                    root_out[128 + j] = cn;
                } else if (OP) {
                    h_out[((size_t)by * n + (size_t)(row & 1) * (n >> 1) + (row >> 1)) * 16 + l15] = (f16)hn;
                    if (!(row & 1))
                        c_out[((size_t)by * (n >> 1) + (row >> 1)) * 16 + l15] = cn;
                } else {
                    h_out[(size_t)row * 128 + j] = (f16)hn;
                    if (!(row & 1))
                        c_out[(size_t)(row >> 1) * 128 + j] = cn;
                }
            }
        }
    }
}

// ---------------- staged tile (big levels d>=11, full tiles) ----------------
// Per-wave LDS A slab: 2 bufs x 4096 B, [64 rows][4 granules of 16 B],
// granule swizzle s(row) = (row>>1)&3 (XOR). No barriers; vmcnt-counted.
__device__ __forceinline__ void stage_chunk(
    const f16* __restrict__ embH, const f16* __restrict__ h_in,
    char* __restrict__ AsW, int buf, int kci, int n, int row0,
    int lane, int gsrc, int srow)
{
    char* dst = AsW + buf * 4096;
    if (kci < 4) {
        const char* eb = (const char*)embH + ((size_t)(n - 1) + row0) * 256 + kci * 64 + gsrc * 16;
        #pragma unroll
        for (int t = 0; t < 4; ++t)
            load_lds_16(eb + ((size_t)(t * 16 + srow)) * 256, dst + t * 1024);
    } else {
        int k0 = (kci - 4) * 32;
        int par = k0 >> 7;
        int cb = k0 & 127;
        int p = (cb >> 4) + (gsrc >> 1);
        const char* hb = (const char*)h_in
            + ((size_t)p * 2 * n + (size_t)par * n + row0) * 32 + (gsrc & 1) * 16;
        #pragma unroll
        for (int t = 0; t < 4; ++t)
            load_lds_16(hb + ((size_t)(t * 16 + srow)) * 32, dst + t * 1024);
    }
}

template <int NCH>
__device__ __forceinline__ void tile_staged(
    const f16* __restrict__ embH, const f16* __restrict__ Bs,
    char* __restrict__ AsW,
    int n, int row0, int lane, int l15, int kq, int j, int by,
    float bi, float bfv, float bg, float bo,
    const f16* __restrict__ h_in, const float* __restrict__ c_in,
    f16* __restrict__ h_out, float* __restrict__ c_out)
{
    const int gsrc = (lane & 3) ^ ((lane >> 3) & 3);  // staged source granule
    const int srow = lane >> 2;                       // staged row within 16
    const int gsel = kq ^ ((l15 >> 1) & 3);           // read-side granule

    f32x4 acc[4][4];
    #pragma unroll
    for (int a = 0; a < 4; ++a)
        #pragma unroll
        for (int b = 0; b < 4; ++b) acc[a][b] = (f32x4)0.f;

    // c prefetch first (oldest in vmcnt queue)
    float cpre[4][4];
    if (NCH == 12) {
        #pragma unroll
        for (int mi = 0; mi < 4; ++mi) {
            #pragma unroll
            for (int r = 0; r < 4; ++r) {
                int row = row0 + mi * 16 + kq * 4 + r;
                cpre[mi][r] = c_in[((size_t)by * n + row) * 16 + l15];
            }
        }
    }

    stage_chunk(embH, h_in, AsW, 0, 0, n, row0, lane, gsrc, srow);
    stage_chunk(embH, h_in, AsW, 1, 1, n, row0, lane, gsrc, srow);

    #pragma unroll
    for (int kci = 0; kci < NCH; ++kci) {
        if (kci + 1 < NCH) asm volatile("s_waitcnt vmcnt(4)" ::: "memory");
        else               asm volatile("s_waitcnt vmcnt(0)" ::: "memory");
        __builtin_amdgcn_sched_barrier(0);

        const f16* slab = (const f16*)(AsW + (kci & 1) * 4096);
        f16x8 a0 = *(const f16x8*)&slab[(0 * 16 + l15) * 32 + gsel * 8];
        f16x8 a1 = *(const f16x8*)&slab[(1 * 16 + l15) * 32 + gsel * 8];
        f16x8 a2 = *(const f16x8*)&slab[(2 * 16 + l15) * 32 + gsel * 8];
        f16x8 a3 = *(const f16x8*)&slab[(3 * 16 + l15) * 32 + gsel * 8];
        f16x8 bf[4];
        #pragma unroll
        for (int g = 0; g < 4; ++g)
            bf[g] = *(const f16x8*)&Bs[((kci * 4 + kq) * 64 + g * 16 + l15) * 8];

        #pragma unroll
        for (int g = 0; g < 4; ++g) {
            acc[0][g] = __builtin_amdgcn_mfma_f32_16x16x32_f16(a0, bf[g], acc[0][g], 0, 0, 0);
            acc[1][g] = __builtin_amdgcn_mfma_f32_16x16x32_f16(a1, bf[g], acc[1][g], 0, 0, 0);
            acc[2][g] = __builtin_amdgcn_mfma_f32_16x16x32_f16(a2, bf[g], acc[2][g], 0, 0, 0);
            acc[3][g] = __builtin_amdgcn_mfma_f32_16x16x32_f16(a3, bf[g], acc[3][g], 0, 0, 0);
        }

        if (kci + 2 < NCH) {
            // buf (kci&1) fully consumed once LDS reads drain; then restage.
            asm volatile("s_waitcnt lgkmcnt(0)" ::: "memory");
            __builtin_amdgcn_sched_barrier(0);
            stage_chunk(embH, h_in, AsW, kci & 1, kci + 2, n, row0, lane, gsrc, srow);
        }
    }

    #pragma unroll
    for (int mi = 0; mi < 4; ++mi) {
        #pragma unroll
        for (int r = 0; r < 4; ++r) {
            int row = row0 + mi * 16 + kq * 4 + r;
            float gi = acc[mi][0][r] + bi;
            float gf = acc[mi][1][r] + bfv;
            float gg = acc[mi][2][r] + bg;
            float go = acc[mi][3][r] + bo;
            float cl = (NCH == 4) ? 0.f : cpre[mi][r];
            float cn = sigf(gf) * cl + sigf(gi) * tanh_fast(gg);
            float hn = sigf(go) * tanh_fast(cn);
            h_out[((size_t)by * n + (size_t)(row & 1) * (n >> 1) + (row >> 1)) * 16 + l15] = (f16)hn;
            if (!(row & 1))
                c_out[((size_t)by * (n >> 1) + (row >> 1)) * 16 + l15] = cn;
        }
    }
}

// Hierarchical grid barrier, agent-scope counters — proven rounds 8/9/11.
__device__ __forceinline__ void gbar(unsigned* sync, unsigned xcc,
                                     unsigned phase, unsigned Gx) {
    __syncthreads();
    if (threadIdx.x == 0) {
        unsigned old = __hip_atomic_fetch_add(&sync[XARR(xcc)], 1u,
                                              __ATOMIC_RELAXED, __HIP_MEMORY_SCOPE_AGENT);
        if (old == phase * Gx - 1u)
            __hip_atomic_fetch_add(&sync[GBARI], 1u,
                                   __ATOMIC_RELAXED, __HIP_MEMORY_SCOPE_AGENT);
        while (__hip_atomic_load(&sync[GBARI], __ATOMIC_RELAXED,
                                 __HIP_MEMORY_SCOPE_AGENT) < phase * 8u)
            __builtin_amdgcn_s_sleep(32);
        asm volatile("buffer_inv sc0" ::: "memory");
    }
    __syncthreads();
}

__global__ __launch_bounds__(256, 2) void mega(
    const f16* __restrict__ embH,
    const f16* __restrict__ Bp, const float* __restrict__ biasP,
    char* __restrict__ H, char* __restrict__ C,
    float* __restrict__ root_out, unsigned* __restrict__ sync)
{
    __shared__ __align__(16) f16 Bs[24576];        // 48 KB
    __shared__ __align__(16) f16 As[4][2][2048];   // 32 KB (4 waves x 2 x 4 KB)
    unsigned* meta = (unsigned*)&As[0][0][0];      // aliased: used pre-staging only

    const int tid = threadIdx.x;
    const int lane = tid & 63;
    const int w = tid >> 6;
    const int l15 = lane & 15;
    const int kq = lane >> 4;

    unsigned xcc;
    asm volatile("s_getreg_b32 %0, hwreg(HW_REG_XCC_ID)" : "=s"(xcc));
    xcc &= 7u;

    // ---- init (poison-tolerant) + XCD ticket + global count ----
    if (blockIdx.x == 0 && tid == 0) {
        for (int x = 0; x < 8; ++x) {
            __hip_atomic_store(&sync[GCNT(x)], 0u, __ATOMIC_RELAXED, __HIP_MEMORY_SCOPE_AGENT);
            __hip_atomic_store(&sync[XARR(x)], 0u, __ATOMIC_RELAXED, __HIP_MEMORY_SCOPE_AGENT);
        }
        __hip_atomic_store(&sync[TOTALI], 0u, __ATOMIC_RELAXED, __HIP_MEMORY_SCOPE_AGENT);
        __hip_atomic_store(&sync[DONEI], 0u, __ATOMIC_RELAXED, __HIP_MEMORY_SCOPE_AGENT);
        __hip_atomic_store(&sync[GBARI], 0u, __ATOMIC_RELAXED, __HIP_MEMORY_SCOPE_AGENT);
        __hip_atomic_store(&sync[FBARI], 0u, __ATOMIC_RELAXED, __HIP_MEMORY_SCOPE_AGENT);
        __hip_atomic_store(&sync[MAGICI], MAGIC, __ATOMIC_RELEASE, __HIP_MEMORY_SCOPE_AGENT);
    }
    if (tid == 0) {
        while (__hip_atomic_load(&sync[MAGICI], __ATOMIC_RELAXED,
                                 __HIP_MEMORY_SCOPE_AGENT) != MAGIC)
            __builtin_amdgcn_s_sleep(32);
        unsigned r = __hip_atomic_fetch_add(&sync[GCNT(xcc)], 1u,
                                            __ATOMIC_RELAXED, __HIP_MEMORY_SCOPE_AGENT);
        asm volatile("s_waitcnt vmcnt(0)" ::: "memory");
        __hip_atomic_fetch_add(&sync[TOTALI], 1u,
                               __ATOMIC_RELAXED, __HIP_MEMORY_SCOPE_AGENT);
        while (__hip_atomic_load(&sync[TOTALI], __ATOMIC_RELAXED,
                                 __HIP_MEMORY_SCOPE_AGENT) < 512u)
            __builtin_amdgcn_s_sleep(32);
        meta[0] = r;
        meta[1] = __hip_atomic_load(&sync[GCNT(xcc)], __ATOMIC_RELAXED,
                                    __HIP_MEMORY_SCOPE_AGENT);
    }
    __syncthreads();
    const unsigned rank = meta[0];
    const unsigned Gx = meta[1];
    const int by = (int)(rank & 7u);
    const int strm = (int)(rank >> 3);
    const int nstr = (int)((Gx - (unsigned)by + 7u) >> 3);
    __syncthreads();   // everyone has read meta before As is staged over

    {   // B slice -> LDS exactly once for all levels
        const char* gB = (const char*)(Bp + (size_t)by * 24576);
        char* lB = (char*)Bs;
        #pragma unroll
        for (int i = 0; i < 12; ++i)
            load_lds_16(gB + ((size_t)(i * 256 + tid)) * 16,
                        lB + ((size_t)(i * 256 + w * 64)) * 16);
    }
    __syncthreads();   // drain B DMA

    const int j = by * 16 + l15;
    const float bi = biasP[by * 64 + 0 + l15];
    const float bfv = biasP[by * 64 + 16 + l15];
    const float bg = biasP[by * 64 + 32 + l15];
    const float bo = biasP[by * 64 + 48 + l15];
    char* AsW = (char*)&As[w][0][0];

    // ---- XCD-local levels d=17..3 ----
    unsigned phase = 0;
    for (int d = 17; d >= 3; --d) {
        const int n = 1 << d;
        const int chunk = n >> 3;
        const int base = (int)xcc * chunk;
        const f16* h_in = hLvl(H, d + 1 < 18 ? d + 1 : 17);
        const float* c_in = cLvl(C, d + 1 < 18 ? d + 1 : 17);
        f16* h_out = hLvl(H, d);
        float* c_out = cLvl(C, d);

        if (d == 17) {
            for (int t = strm; t < 64; t += nstr) {
                int row0 = base + t * 256 + w * 64;
                tile_staged<4>(embH, Bs, AsW, n, row0, lane, l15, kq, j, by,
                               bi, bfv, bg, bo, h_in, c_in, h_out, c_out);
            }
        } else if (d >= 11) {
            const int T = 1 << (d - 11);
            for (int t = strm; t < T; t += nstr) {
                int row0 = base + t * 256 + w * 64;
                tile_staged<12>(embH, Bs, AsW, n, row0, lane, l15, kq, j, by,
                                bi, bfv, bg, bo, h_in, c_in, h_out, c_out);
            }
        } else if (d >= 5) {
            if (strm == 0 && w * 64 < chunk) {
                int row0 = base + w * 64;
                tile_compute<12, 1, 2, 1>(embH, Bs, n, row0, base + chunk, l15, kq, j, by,
                                          bi, bfv, bg, bo, h_in, c_in, h_out, c_out, nullptr);
            }
        } else if (d == 4) {
            if (strm == 0 && w * 64 < chunk) {
                int row0 = base + w * 64;
                tile_compute<12, 1, 2, 0>(embH, Bs, n, row0, base + chunk, l15, kq, j, by,
                                          bi, bfv, bg, bo, h_in, c_in, h_out, c_out, nullptr);
            }
        } else {   // d == 3: child level 4 is row-major
            if (strm == 0 && w * 64 < chunk) {
                int row0 = base + w * 64;
                tile_compute<12, 1, 0, 0>(embH, Bs, n, row0, base + chunk, l15, kq, j, by,
                                          bi, bfv, bg, bo, h_in, c_in, h_out, c_out, nullptr);
            }
        }

        ++phase;
        gbar(sync, xcc, phase, Gx);
    }

    // ---- publish d=3 results cross-XCD (8 threadfences total) ----
    if (rank == 0 && tid == 0) {
        __threadfence();
        __hip_atomic_fetch_add(&sync[DONEI], 1u,
                               __ATOMIC_RELAXED, __HIP_MEMORY_SCOPE_AGENT);
    }

    const bool fin = (xcc == 0u) && (rank < 8u);
    if (!fin) return;

    if (tid == 0) {
        while (__hip_atomic_load(&sync[DONEI], __ATOMIC_RELAXED,
                                 __HIP_MEMORY_SCOPE_AGENT) < 8u)
            __builtin_amdgcn_s_sleep(32);
        __threadfence();
    }
    __syncthreads();

    // ---- finals: d=2,1,0 on 8 XCD0 blocks (levels 3,2,1 row-major) ----
    unsigned fphase = 0;
    for (int d = 2; d >= 0; --d) {
        const int n = 1 << d;
        const f16* h_in = hLvl(H, d + 1);
        const float* c_in = cLvl(C, d + 1);
        f16* h_out = hLvl(H, d);
        float* c_out = cLvl(C, d);
        if (w == 0)
            tile_compute<12, 1, 0, 0>(embH, Bs, n, 0, n, l15, kq, j, by,
                                      bi, bfv, bg, bo, h_in, c_in, h_out, c_out,
                                      (d == 0) ? (float*)root_out : nullptr);
        if (d > 0) {
            ++fphase;
            __syncthreads();
            if (tid == 0) {
                __hip_atomic_fetch_add(&sync[FBARI], 1u,
                                       __ATOMIC_RELAXED, __HIP_MEMORY_SCOPE_AGENT);
                while (__hip_atomic_load(&sync[FBARI], __ATOMIC_RELAXED,
                                         __HIP_MEMORY_SCOPE_AGENT) < fphase * 8u)
                    __builtin_amdgcn_s_sleep(4);
                asm volatile("buffer_inv sc0" ::: "memory");
            }
            __syncthreads();
        }
    }
}

extern "C" void kernel_launch(void* const* d_in, const int* in_sizes, int n_in,
                              void* d_out, int out_size, void* d_ws, size_t ws_size,
                              hipStream_t stream) {
    const float* emb  = (const float*)d_in[0];
    const float* W_ih = (const float*)d_in[1];
    const float* W_hh = (const float*)d_in[2];
    const float* b_ih = (const float*)d_in[3];
    const float* b_hh = (const float*)d_in[4];

    char* wsb = (char*)d_ws;
    f16*   Bp    = (f16*)wsb;                      // 393216 B
    float* biasP = (float*)(wsb + 393216);         // 2048 B
    unsigned* syncp = (unsigned*)(wsb + 397312);   // 4096 B reserved
    f16* embH = (f16*)(wsb + 1048576);             // 64 MiB (f16 emb)
    char* H = wsb + 1048576 + 67108864;            // 64 MiB per-level h
    char* C = wsb + 1048576 + 2 * 67108864;        // 64 MiB per-level c
    if (ws_size < 1048576 + 3 * 67108864) return;

    pack_weights<<<768, 256, 0, stream>>>(W_ih, W_hh, b_ih, b_hh, Bp, biasP);
    emb_cvt<<<16384, 256, 0, stream>>>(emb, (f16*)embH);
    mega<<<512, 256, 0, stream>>>(embH, Bp, biasP, H, C, (float*)d_out, syncp);
}